// Round 11
// baseline (263.447 us; speedup 1.0000x reference)
//
#include <hip/hip_runtime.h>
#include <hip/hip_bf16.h>
#include <stdint.h>

// Problem constants
#define TLEN 4096
#define DMm  2048
#define DD   4096
#define DGg  512
#define BT   8192          // B*T
#define DW   16384         // D*W

typedef __attribute__((ext_vector_type(8))) short bf16x8;
typedef __attribute__((ext_vector_type(4))) float f32x4;

__device__ __forceinline__ unsigned short f2bf(float f) {
    union { float f; unsigned u; } c; c.f = f;
    unsigned u = c.u;
    unsigned r = (u + 0x7FFFu + ((u >> 16) & 1u)) >> 16;   // RNE
    return (unsigned short)r;
}

// ---------------- fused cast f32 -> bf16 for gen|w1|w2 (contiguous in ws) ----
#define NB1 (BT * DMm / 4)
#define NB2 (DGg * DMm / 4)
#define NB3 (DW * DGg / 4)
__global__ void cast_all_kernel(const float* __restrict__ g,
                                const float* __restrict__ w1,
                                const float* __restrict__ w2,
                                unsigned short* __restrict__ o) {
    int i = blockIdx.x * blockDim.x + threadIdx.x;
    if (i >= NB1 + NB2 + NB3) return;
    const float* src; int j = i;
    if (j < NB1) { src = g; }
    else if (j < NB1 + NB2) { src = w1; j -= NB1; }
    else { src = w2; j -= NB1 + NB2; }
    float4 v = reinterpret_cast<const float4*>(src)[j];
    ushort4 u;
    u.x = f2bf(v.x); u.y = f2bf(v.y); u.z = f2bf(v.z); u.w = f2bf(v.w);
    reinterpret_cast<ushort4*>(o)[i] = u;
}

#define GLDS16(gp, lp)                                                         \
    __builtin_amdgcn_global_load_lds(                                          \
        (__attribute__((address_space(1))) const void*)(gp),                   \
        (__attribute__((address_space(3))) void*)(lp), 16, 0, 0)

#define VMCNT(n) asm volatile("s_waitcnt vmcnt(" #n ")" ::: "memory")
#define SBAR()   __builtin_amdgcn_s_barrier()
#define SCHED0() __builtin_amdgcn_sched_barrier(0)

// ---------------- GEMM1: h = silu(gen @ w1^T), bf16 out (unchanged) ----------
__global__ __launch_bounds__(256) void gemm1_silu_kernel(
    const unsigned short* __restrict__ A,
    const unsigned short* __restrict__ Bm,
    unsigned short* __restrict__ H)
{
    __shared__ short smA[128 * 32];
    __shared__ short smB[128 * 32];
    const int m0   = blockIdx.y * 128;
    const int n0   = blockIdx.x * 128;
    const int lane = threadIdx.x & 63;
    const int wave = threadIdx.x >> 6;
    const int wm   = wave >> 1, wn = wave & 1;

    const int c0 = wave * 64 + lane;
    const int c1 = c0 + 256;
    const int rA0 = m0 + (c0 >> 2), rA1 = m0 + (c1 >> 2);
    const int rB0 = n0 + (c0 >> 2), rB1 = n0 + (c1 >> 2);
    const int ko0 = (c0 & 3) * 8,  ko1 = (c1 & 3) * 8;

    f32x4 acc[4][4] = {};

    for (int k0 = 0; k0 < DMm; k0 += 32) {
        GLDS16(A  + (size_t)rA0 * DMm + k0 + ko0, smA + wave * 512);
        GLDS16(A  + (size_t)rA1 * DMm + k0 + ko1, smA + 2048 + wave * 512);
        GLDS16(Bm + (size_t)rB0 * DMm + k0 + ko0, smB + wave * 512);
        GLDS16(Bm + (size_t)rB1 * DMm + k0 + ko1, smB + 2048 + wave * 512);
        __syncthreads();

        const int la = lane & 15, ko = (lane >> 4) * 8;
        bf16x8 af[4], bfr[4];
#pragma unroll
        for (int mm = 0; mm < 4; ++mm)
            af[mm] = *reinterpret_cast<const bf16x8*>(&smA[(wm * 64 + mm * 16 + la) * 32 + ko]);
#pragma unroll
        for (int nn = 0; nn < 4; ++nn)
            bfr[nn] = *reinterpret_cast<const bf16x8*>(&smB[(wn * 64 + nn * 16 + la) * 32 + ko]);
#pragma unroll
        for (int mm = 0; mm < 4; ++mm)
#pragma unroll
            for (int nn = 0; nn < 4; ++nn)
                acc[mm][nn] = __builtin_amdgcn_mfma_f32_16x16x32_bf16(
                    af[mm], bfr[nn], acc[mm][nn], 0, 0, 0);
        __syncthreads();
    }

#pragma unroll
    for (int mm = 0; mm < 4; ++mm) {
        int rowB = m0 + wm * 64 + mm * 16 + (lane >> 4) * 4;
#pragma unroll
        for (int nn = 0; nn < 4; ++nn) {
            int colG = n0 + wn * 64 + nn * 16 + (lane & 15);
#pragma unroll
            for (int j = 0; j < 4; ++j) {
                float v = acc[mm][nn][j];
                float s = v / (1.0f + __expf(-v));
                H[(size_t)(rowB + j) * DGg + colG] = f2bf(s);
            }
        }
    }
}

// ===== GEMM2 fused: 8-phase (m-half balanced), 256n x 256t, BK=64 =====
// D[n][t] = sum_k W2b[n][k] * Hb[t][k]   (n = 4d+w; conv taps w = acc reg idx j)
// 8 waves (wm 0..1 x wn 0..3); wave 128n x 64t; acc[8][4] f32x4.
// K = 512 -> 8 K-tiles (BK=64) -> 4 iterations x 8 phases.
// Phase (par,kh,mh): mh==0 reads aF[0..3] + bF[0..3] (8 ds_read_b128),
// mh==1 reads aF[4..7] (4 reads; bF persists in regs).  16 MFMA each.
// No manual lgkmcnt: plain C++ ds_reads -> compiler emits counted lgkm
// waits inside the MFMA cluster (early MFMAs overlap tail reads).
// Staging: 1 half-tile (2 gload_lds/thread) per phase, 3 half-periods ahead.
// vmcnt(4) only at ph3 (certifies tile 2i+1) and ph7 (certifies 2i+2);
// tail vmcnt(0) at i=3/ph3.  vmcnt ALWAYS before the closing barrier.
// LDS: A[par][kh][256 rows][64B] = 64K @0; B same @65536;
// post-loop overlay X f32[259][68] @0, Y f32[256][68] @70448 (140080 peak).
#define LDS_B2 65536

__global__ __launch_bounds__(512, 2) void gemm2_conv_silu_kernel(
    const unsigned short* __restrict__ Hb,
    const unsigned short* __restrict__ W2b,
    const float* __restrict__ b2,
    const float* __restrict__ x,
    float* __restrict__ out)
{
    __shared__ __attribute__((aligned(16))) char lds[140080];
    const int tid  = threadIdx.x;
    const int lane = tid & 63, wave = tid >> 6;
    const int wm   = wave >> 2, wn = wave & 3;
    const int la   = lane & 15, hi = lane >> 4;

    // XCD-aware swizzle (2048 blocks, %8==0 -> bijective); t fast within XCD
    int bid = blockIdx.x;
    int swz = (bid & 7) * 256 + (bid >> 3);
    const int n0 = (swz >> 5) * 256;   // 64 n-tiles
    const int t0 = (swz & 31) * 256;   // 32 t-tiles
    const int d0 = n0 >> 2;

    const int srow = lane >> 2;                               // 0..15
    const int scol = ((lane & 3) ^ ((srow >> 1) & 3)) * 8;    // pre-swizzled src col

    // stage one half-tile (256 rows x 32 k) = 2 gload_lds per thread
    auto stageA = [&](int tk, int kh) {
#pragma unroll
        for (int q = 0; q < 2; ++q) {
            int chunk = wave * 2 + q, row = chunk * 16 + srow;   // 0..255
            GLDS16(W2b + (size_t)(n0 + row) * DGg + tk * 64 + kh * 32 + scol,
                   lds + (tk & 1) * 32768 + kh * 16384 + chunk * 1024);
        }
    };
    auto stageB = [&](int tk, int kh) {
#pragma unroll
        for (int q = 0; q < 2; ++q) {
            int chunk = wave * 2 + q, row = chunk * 16 + srow;
            GLDS16(Hb + (size_t)(t0 + row) * DGg + tk * 64 + kh * 32 + scol,
                   lds + LDS_B2 + (tk & 1) * 32768 + kh * 16384 + chunk * 1024);
        }
    };

    f32x4 acc[8][4] = {};
    const int slotb = (hi ^ ((la >> 1) & 3)) * 16;   // swizzled 16B slot
    bf16x8 bF[4];                                    // persists phaseA -> phaseB

    // phase mh==0: read aF[0..3] + bF[0..3]; MFMA m0-3 x nr0-3
    auto phaseA = [&](int par, int kh, auto stage, bool v4, bool v0) {
        const char* aB = lds + par * 32768 + kh * 16384 + (wm * 128 + la) * 64 + slotb;
        const char* bB = lds + LDS_B2 + par * 32768 + kh * 16384 + (wn * 64 + la) * 64 + slotb;
        bf16x8 aF[4];
#pragma unroll
        for (int m = 0; m < 4; ++m)
            aF[m] = *reinterpret_cast<const bf16x8*>(aB + m * 1024);
#pragma unroll
        for (int nr = 0; nr < 4; ++nr)
            bF[nr] = *reinterpret_cast<const bf16x8*>(bB + nr * 1024);
        stage();
        if (v4) VMCNT(4);
        if (v0) VMCNT(0);
        SBAR(); SCHED0();
        __builtin_amdgcn_s_setprio(1);
#pragma unroll
        for (int m = 0; m < 4; ++m)
#pragma unroll
            for (int nr = 0; nr < 4; ++nr)
                acc[m][nr] = __builtin_amdgcn_mfma_f32_16x16x32_bf16(
                    aF[m], bF[nr], acc[m][nr], 0, 0, 0);
        __builtin_amdgcn_s_setprio(0);
        SBAR();
    };
    // phase mh==1: read aF[4..7]; MFMA m4-7 x nr0-3 (bF reused)
    auto phaseB = [&](int par, int kh, auto stage, bool v4, bool v0) {
        const char* aB = lds + par * 32768 + kh * 16384 + (wm * 128 + la) * 64 + slotb;
        bf16x8 aF[4];
#pragma unroll
        for (int m = 0; m < 4; ++m)
            aF[m] = *reinterpret_cast<const bf16x8*>(aB + 4096 + m * 1024);
        stage();
        if (v4) VMCNT(4);
        if (v0) VMCNT(0);
        SBAR(); SCHED0();
        __builtin_amdgcn_s_setprio(1);
#pragma unroll
        for (int m = 0; m < 4; ++m)
#pragma unroll
            for (int nr = 0; nr < 4; ++nr)
                acc[4 + m][nr] = __builtin_amdgcn_mfma_f32_16x16x32_bf16(
                    aF[m], bF[nr], acc[4 + m][nr], 0, 0, 0);
        __builtin_amdgcn_s_setprio(0);
        SBAR();
    };

    // ---- prologue: halves {t0:kh0, t0:kh1, t1:kh0} of A and B ----
    stageA(0, 0); stageB(0, 0);
    stageA(0, 1); stageB(0, 1);
    stageA(1, 0); stageB(1, 0);
    VMCNT(4);   // tile 0 (both halves) certified for all waves after barrier
    SBAR();

    // ---- main loop: 4 iterations x 8 phases ----
#pragma unroll
    for (int i = 0; i < 4; ++i) {
        const int s2 = 2 * i + 2, s3 = 2 * i + 3;
        phaseA(0, 0, [&]{ stageA(2 * i + 1, 1); }, false, false);            // ph0
        phaseB(0, 0, [&]{ stageB(2 * i + 1, 1); }, false, false);            // ph1
        phaseA(0, 1, [&]{ if (s2 < 8) stageA(s2, 0); }, false, false);       // ph2
        phaseB(0, 1, [&]{ if (s2 < 8) stageB(s2, 0); }, i < 3, i == 3);      // ph3
        phaseA(1, 0, [&]{ if (s2 < 8) stageA(s2, 1); }, false, false);       // ph4
        phaseB(1, 0, [&]{ if (s2 < 8) stageB(s2, 1); }, false, false);       // ph5
        phaseA(1, 1, [&]{ if (s3 < 8) stageA(s3, 0); }, false, false);       // ph6
        phaseB(1, 1, [&]{ if (s3 < 8) stageB(s3, 0); }, i < 3, false);       // ph7
    }

    // ---- x loads (post-loop; ride in regs until overlay is safe) ----
    float4 xv[9];
#pragma unroll
    for (int k = 0; k < 9; ++k) {
        int c = tid + k * 512;                   // < 4144 = 259 rows * 16 chunks
        float4 v = make_float4(0.f, 0.f, 0.f, 0.f);
        if (c < 4144) {
            int row = c >> 4, q = c & 15;
            int rg = t0 - 3 + row;
            if (rg >= 0 && (rg >> 12) == (t0 >> 12))   // zero across batch boundary
                v = *reinterpret_cast<const float4*>(&x[(size_t)rg * DD + d0 + q * 4]);
        }
        xv[k] = v;
    }
    __syncthreads();   // all K-loop LDS reads done; overlay X/Y

    float* smX = reinterpret_cast<float*>(lds);
#pragma unroll
    for (int k = 0; k < 9; ++k) {
        int c = tid + k * 512;
        if (c < 4144) {
            int row = c >> 4, q = c & 15;
            *reinterpret_cast<float4*>(&smX[row * 68 + q * 4]) = xv[k];
        }
    }
    __syncthreads();

    // ---- epilogue: bias + conv taps (reg idx j) + silu -> smY ----
    float4 bb[8];
#pragma unroll
    for (int m = 0; m < 8; ++m)
        bb[m] = *reinterpret_cast<const float4*>(&b2[n0 + wm * 128 + m * 16 + hi * 4]);

    float* smY = reinterpret_cast<float*>(lds + 70448);
#pragma unroll
    for (int nr = 0; nr < 4; ++nr) {
        int tl = wn * 64 + nr * 16 + la;
#pragma unroll
        for (int m = 0; m < 8; ++m) {
            int dl = wm * 32 + m * 4 + hi;
            float pv =
                  (acc[m][nr][0] + bb[m].x) * smX[(tl + 0) * 68 + dl]
                + (acc[m][nr][1] + bb[m].y) * smX[(tl + 1) * 68 + dl]
                + (acc[m][nr][2] + bb[m].z) * smX[(tl + 2) * 68 + dl]
                + (acc[m][nr][3] + bb[m].w) * smX[(tl + 3) * 68 + dl];
            smY[tl * 68 + dl] = pv / (1.0f + __expf(-pv));
        }
    }
    __syncthreads();

    // ---- coalesced store: 256 rows x 64 f32 (256 B per row) ----
    for (int c = tid; c < 256 * 16; c += 512) {
        int row = c >> 4, q = c & 15;
        float4 v = *reinterpret_cast<const float4*>(&smY[row * 68 + q * 4]);
        *reinterpret_cast<float4*>(&out[(size_t)(t0 + row) * DD + d0 + q * 4]) = v;
    }
}

extern "C" void kernel_launch(void* const* d_in, const int* in_sizes, int n_in,
                              void* d_out, int out_size, void* d_ws, size_t ws_size,
                              hipStream_t stream) {
    const float* x   = (const float*)d_in[0];
    const float* gen = (const float*)d_in[1];
    const float* w1  = (const float*)d_in[2];
    const float* w2  = (const float*)d_in[3];
    const float* b2  = (const float*)d_in[4];
    float* out = (float*)d_out;

    char* ws = (char*)d_ws;
    size_t off = 0;
    unsigned short* gen_b = (unsigned short*)(ws + off); off += (size_t)BT * DMm * 2;
    unsigned short* w1_b  = (unsigned short*)(ws + off); off += (size_t)DGg * DMm * 2;
    unsigned short* w2_b  = (unsigned short*)(ws + off); off += (size_t)DW * DGg * 2;
    unsigned short* h_b   = (unsigned short*)(ws + off); off += (size_t)BT * DGg * 2;

    int total4 = NB1 + NB2 + NB3;
    cast_all_kernel<<<(total4 + 255) / 256, 256, 0, stream>>>(gen, w1, w2, gen_b);

    gemm1_silu_kernel<<<dim3(DGg / 128, BT / 128), 256, 0, stream>>>(gen_b, w1_b, h_b);
    gemm2_conv_silu_kernel<<<2048, 512, 0, stream>>>(h_b, w2_b, b2, x, out);
}

// Round 12
// 253.040 us; speedup vs baseline: 1.0411x; 1.0411x over previous
//
#include <hip/hip_runtime.h>
#include <hip/hip_bf16.h>
#include <stdint.h>

// Problem constants
#define TLEN 4096
#define DMm  2048
#define DD   4096
#define DGg  512
#define BT   8192          // B*T
#define DW   16384         // D*W

typedef __attribute__((ext_vector_type(8))) short bf16x8;
typedef __attribute__((ext_vector_type(4))) float f32x4;

__device__ __forceinline__ unsigned short f2bf(float f) {
    union { float f; unsigned u; } c; c.f = f;
    unsigned u = c.u;
    unsigned r = (u + 0x7FFFu + ((u >> 16) & 1u)) >> 16;   // RNE
    return (unsigned short)r;
}

// ---------------- fused cast f32 -> bf16 for gen|w1|w2 (contiguous in ws) ----
#define NB1 (BT * DMm / 4)
#define NB2 (DGg * DMm / 4)
#define NB3 (DW * DGg / 4)
__global__ void cast_all_kernel(const float* __restrict__ g,
                                const float* __restrict__ w1,
                                const float* __restrict__ w2,
                                unsigned short* __restrict__ o) {
    int i = blockIdx.x * blockDim.x + threadIdx.x;
    if (i >= NB1 + NB2 + NB3) return;
    const float* src; int j = i;
    if (j < NB1) { src = g; }
    else if (j < NB1 + NB2) { src = w1; j -= NB1; }
    else { src = w2; j -= NB1 + NB2; }
    float4 v = reinterpret_cast<const float4*>(src)[j];
    ushort4 u;
    u.x = f2bf(v.x); u.y = f2bf(v.y); u.z = f2bf(v.z); u.w = f2bf(v.w);
    reinterpret_cast<ushort4*>(o)[i] = u;
}

#define GLDS16(gp, lp)                                                         \
    __builtin_amdgcn_global_load_lds(                                          \
        (__attribute__((address_space(1))) const void*)(gp),                   \
        (__attribute__((address_space(3))) void*)(lp), 16, 0, 0)

#define VMCNT(n) asm volatile("s_waitcnt vmcnt(" #n ")" ::: "memory")
#define SBAR()   __builtin_amdgcn_s_barrier()
#define SCHED0() __builtin_amdgcn_sched_barrier(0)

// ---------------- GEMM1: h = silu(gen @ w1^T), bf16 out (unchanged) ----------
__global__ __launch_bounds__(256) void gemm1_silu_kernel(
    const unsigned short* __restrict__ A,
    const unsigned short* __restrict__ Bm,
    unsigned short* __restrict__ H)
{
    __shared__ short smA[128 * 32];
    __shared__ short smB[128 * 32];
    const int m0   = blockIdx.y * 128;
    const int n0   = blockIdx.x * 128;
    const int lane = threadIdx.x & 63;
    const int wave = threadIdx.x >> 6;
    const int wm   = wave >> 1, wn = wave & 1;

    const int c0 = wave * 64 + lane;
    const int c1 = c0 + 256;
    const int rA0 = m0 + (c0 >> 2), rA1 = m0 + (c1 >> 2);
    const int rB0 = n0 + (c0 >> 2), rB1 = n0 + (c1 >> 2);
    const int ko0 = (c0 & 3) * 8,  ko1 = (c1 & 3) * 8;

    f32x4 acc[4][4] = {};

    for (int k0 = 0; k0 < DMm; k0 += 32) {
        GLDS16(A  + (size_t)rA0 * DMm + k0 + ko0, smA + wave * 512);
        GLDS16(A  + (size_t)rA1 * DMm + k0 + ko1, smA + 2048 + wave * 512);
        GLDS16(Bm + (size_t)rB0 * DMm + k0 + ko0, smB + wave * 512);
        GLDS16(Bm + (size_t)rB1 * DMm + k0 + ko1, smB + 2048 + wave * 512);
        __syncthreads();

        const int la = lane & 15, ko = (lane >> 4) * 8;
        bf16x8 af[4], bfr[4];
#pragma unroll
        for (int mm = 0; mm < 4; ++mm)
            af[mm] = *reinterpret_cast<const bf16x8*>(&smA[(wm * 64 + mm * 16 + la) * 32 + ko]);
#pragma unroll
        for (int nn = 0; nn < 4; ++nn)
            bfr[nn] = *reinterpret_cast<const bf16x8*>(&smB[(wn * 64 + nn * 16 + la) * 32 + ko]);
#pragma unroll
        for (int mm = 0; mm < 4; ++mm)
#pragma unroll
            for (int nn = 0; nn < 4; ++nn)
                acc[mm][nn] = __builtin_amdgcn_mfma_f32_16x16x32_bf16(
                    af[mm], bfr[nn], acc[mm][nn], 0, 0, 0);
        __syncthreads();
    }

#pragma unroll
    for (int mm = 0; mm < 4; ++mm) {
        int rowB = m0 + wm * 64 + mm * 16 + (lane >> 4) * 4;
#pragma unroll
        for (int nn = 0; nn < 4; ++nn) {
            int colG = n0 + wn * 64 + nn * 16 + (lane & 15);
#pragma unroll
            for (int j = 0; j < 4; ++j) {
                float v = acc[mm][nn][j];
                float s = v / (1.0f + __expf(-v));
                H[(size_t)(rowB + j) * DGg + colG] = f2bf(s);
            }
        }
    }
}

// ===== GEMM2 fused: 256n x 256t, 16 waves (64x64 each), quad-ring BK=32 =====
// D[n][t] = sum_k W2b[n][k] * Hb[t][k]   (n = 4d+w; conv taps w = acc reg idx j)
// 16 waves (wm 0..3 x wn 0..3), wave tile 64n x 64t: acc[4][4] = 64 VGPR ->
// total ~116 regs -> 16 waves/CU = 4 waves/SIMD (vs 2 in rounds 8-11): the
// per-wave lgkm/vmcnt/barrier serialization now overlaps across 2x the waves
// (m114 mechanism).  Per region per wave: 8 ds_read_b128 + 16 MFMA + 1 gload
// per matrix per thread (chunk = wave).
// Ledger (2 loads/thread/tile, order A then B): prologue stages tiles 0,1,2
// (6 loads) -> VMCNT(4) certifies tile 0; region r (0..12) stages r+3 ->
// VMCNT(4) certifies r+1 (tiles r+2, r+3 = 4 loads in flight); r=13 VMCNT(2);
// r=14 VMCNT(0); r=15 bare.  vmcnt ALWAYS before the closing barrier.
// One barrier per region (r8-proven): stage targets par (r-1)&3, whose readers
// all passed region r-1's closing barrier.
// LDS: A[4 par][256 rows][64B] @0 (64K), B same @65536 (64K);
// post-loop overlay X f32[259][68] @0, Y f32[256][68] @70448 (140080 peak).
#define LDS_B2 65536

__global__ __launch_bounds__(1024, 4) void gemm2_conv_silu_kernel(
    const unsigned short* __restrict__ Hb,
    const unsigned short* __restrict__ W2b,
    const float* __restrict__ b2,
    const float* __restrict__ x,
    float* __restrict__ out)
{
    __shared__ __attribute__((aligned(16))) char lds[140080];
    const int tid  = threadIdx.x;
    const int lane = tid & 63, wave = tid >> 6;
    const int wm   = wave >> 2, wn = wave & 3;
    const int la   = lane & 15, hi = lane >> 4;

    // XCD-aware swizzle (2048 blocks, %8==0 -> bijective); t fast within XCD
    int bid = blockIdx.x;
    int swz = (bid & 7) * 256 + (bid >> 3);
    const int n0 = (swz >> 5) * 256;   // 64 n-tiles
    const int t0 = (swz & 31) * 256;   // 32 t-tiles
    const int d0 = n0 >> 2;

    const int srow = lane >> 2;                               // 0..15
    const int scol = ((lane & 3) ^ ((srow >> 1) & 3)) * 8;    // pre-swizzled src col

    // one 16B gload_lds per thread per matrix: wave covers rows wave*16..+15
    auto stageA = [&](int tk, int p) {
        int row = wave * 16 + srow;                           // 0..255
        GLDS16(W2b + (size_t)(n0 + row) * DGg + tk * 32 + scol,
               lds + p * 16384 + wave * 1024);
    };
    auto stageB = [&](int tk, int p) {
        int row = wave * 16 + srow;
        GLDS16(Hb + (size_t)(t0 + row) * DGg + tk * 32 + scol,
               lds + LDS_B2 + p * 16384 + wave * 1024);
    };

    f32x4 acc[4][4] = {};
    const int slotb = (hi ^ ((la >> 1) & 3)) * 16;   // swizzled 16B slot
    const int aOff  = (wm * 64 + la) * 64 + slotb;
    const int bOff  = LDS_B2 + (wn * 64 + la) * 64 + slotb;

    auto region = [&](int r, bool doStage) {
        const int p = r & 3;
        const char* aB = lds + p * 16384 + aOff;
        const char* bB = lds + p * 16384 + bOff;
        bf16x8 aF[4], bF[4];
#pragma unroll
        for (int m = 0; m < 4; ++m)
            aF[m] = *reinterpret_cast<const bf16x8*>(aB + m * 1024);
#pragma unroll
        for (int nr = 0; nr < 4; ++nr)
            bF[nr] = *reinterpret_cast<const bf16x8*>(bB + nr * 1024);
        if (doStage) { stageA(r + 3, (r + 3) & 3); stageB(r + 3, (r + 3) & 3); }
        SCHED0();   // pin reads+stage above the MFMA cluster
        __builtin_amdgcn_s_setprio(1);
#pragma unroll
        for (int m = 0; m < 4; ++m)
#pragma unroll
            for (int nr = 0; nr < 4; ++nr)
                acc[m][nr] = __builtin_amdgcn_mfma_f32_16x16x32_bf16(
                    aF[m], bF[nr], acc[m][nr], 0, 0, 0);
        __builtin_amdgcn_s_setprio(0);
        SCHED0();
    };

    // ---- prologue: stage tiles 0,1,2 (A,B interleaved) ----
    stageA(0, 0); stageB(0, 0);
    stageA(1, 1); stageB(1, 1);
    stageA(2, 2); stageB(2, 2);
    VMCNT(4);     // tile 0 certified for all waves after the barrier
    SBAR();

    // ---- main loop: 16 regions, counted vmcnt BEFORE each barrier ----
#pragma unroll
    for (int r = 0; r < 13; ++r) {
        region(r, true);
        VMCNT(4);      // certify tile r+1; tiles r+2, r+3 (4 loads) in flight
        SBAR();
    }
    region(13, false); VMCNT(2); SBAR();   // certify tile 14; tile 15 in flight
    region(14, false); VMCNT(0); SBAR();   // certify tile 15
    region(15, false);

    // ---- x loads (post-loop; ride in regs until overlay is safe) ----
    float4 xv[5];
#pragma unroll
    for (int k = 0; k < 5; ++k) {
        int c = tid + k * 1024;                  // < 4144 = 259 rows * 16 chunks
        float4 v = make_float4(0.f, 0.f, 0.f, 0.f);
        if (c < 4144) {
            int row = c >> 4, q = c & 15;
            int rg = t0 - 3 + row;
            if (rg >= 0 && (rg >> 12) == (t0 >> 12))   // zero across batch boundary
                v = *reinterpret_cast<const float4*>(&x[(size_t)rg * DD + d0 + q * 4]);
        }
        xv[k] = v;
    }
    __syncthreads();   // all K-loop LDS reads done; overlay X/Y

    float* smX = reinterpret_cast<float*>(lds);
#pragma unroll
    for (int k = 0; k < 5; ++k) {
        int c = tid + k * 1024;
        if (c < 4144) {
            int row = c >> 4, q = c & 15;
            *reinterpret_cast<float4*>(&smX[row * 68 + q * 4]) = xv[k];
        }
    }
    __syncthreads();

    // ---- epilogue: bias + conv taps (reg idx j) + silu -> smY ----
    float4 bb[4];
#pragma unroll
    for (int m = 0; m < 4; ++m)
        bb[m] = *reinterpret_cast<const float4*>(&b2[n0 + wm * 64 + m * 16 + hi * 4]);

    float* smY = reinterpret_cast<float*>(lds + 70448);
#pragma unroll
    for (int nr = 0; nr < 4; ++nr) {
        int tl = wn * 64 + nr * 16 + la;
#pragma unroll
        for (int m = 0; m < 4; ++m) {
            int dl = wm * 16 + m * 4 + hi;
            float pv =
                  (acc[m][nr][0] + bb[m].x) * smX[(tl + 0) * 68 + dl]
                + (acc[m][nr][1] + bb[m].y) * smX[(tl + 1) * 68 + dl]
                + (acc[m][nr][2] + bb[m].z) * smX[(tl + 2) * 68 + dl]
                + (acc[m][nr][3] + bb[m].w) * smX[(tl + 3) * 68 + dl];
            smY[tl * 68 + dl] = pv / (1.0f + __expf(-pv));
        }
    }
    __syncthreads();

    // ---- coalesced store: 256 rows x 64 f32 (256 B per row) ----
    for (int c = tid; c < 256 * 16; c += 1024) {
        int row = c >> 4, q = c & 15;
        float4 v = *reinterpret_cast<const float4*>(&smY[row * 68 + q * 4]);
        *reinterpret_cast<float4*>(&out[(size_t)(t0 + row) * DD + d0 + q * 4]) = v;
    }
}

extern "C" void kernel_launch(void* const* d_in, const int* in_sizes, int n_in,
                              void* d_out, int out_size, void* d_ws, size_t ws_size,
                              hipStream_t stream) {
    const float* x   = (const float*)d_in[0];
    const float* gen = (const float*)d_in[1];
    const float* w1  = (const float*)d_in[2];
    const float* w2  = (const float*)d_in[3];
    const float* b2  = (const float*)d_in[4];
    float* out = (float*)d_out;

    char* ws = (char*)d_ws;
    size_t off = 0;
    unsigned short* gen_b = (unsigned short*)(ws + off); off += (size_t)BT * DMm * 2;
    unsigned short* w1_b  = (unsigned short*)(ws + off); off += (size_t)DGg * DMm * 2;
    unsigned short* w2_b  = (unsigned short*)(ws + off); off += (size_t)DW * DGg * 2;
    unsigned short* h_b   = (unsigned short*)(ws + off); off += (size_t)BT * DGg * 2;

    int total4 = NB1 + NB2 + NB3;
    cast_all_kernel<<<(total4 + 255) / 256, 256, 0, stream>>>(gen, w1, w2, gen_b);

    gemm1_silu_kernel<<<dim3(DGg / 128, BT / 128), 256, 0, stream>>>(gen_b, w1_b, h_b);
    gemm2_conv_silu_kernel<<<2048, 1024, 0, stream>>>(h_b, w2_b, b2, x, out);
}

// Round 13
// 237.176 us; speedup vs baseline: 1.1108x; 1.0669x over previous
//
#include <hip/hip_runtime.h>
#include <hip/hip_bf16.h>
#include <stdint.h>

// Problem constants
#define TLEN 4096
#define DMm  2048
#define DD   4096
#define DGg  512
#define BT   8192          // B*T
#define DW   16384         // D*W

typedef __attribute__((ext_vector_type(8))) short bf16x8;
typedef __attribute__((ext_vector_type(4))) float f32x4;

__device__ __forceinline__ unsigned short f2bf(float f) {
    union { float f; unsigned u; } c; c.f = f;
    unsigned u = c.u;
    unsigned r = (u + 0x7FFFu + ((u >> 16) & 1u)) >> 16;   // RNE
    return (unsigned short)r;
}

// ---------------- fused cast f32 -> bf16 for gen|w1|w2 (contiguous in ws) ----
#define NB1 (BT * DMm / 4)
#define NB2 (DGg * DMm / 4)
#define NB3 (DW * DGg / 4)
__global__ void cast_all_kernel(const float* __restrict__ g,
                                const float* __restrict__ w1,
                                const float* __restrict__ w2,
                                unsigned short* __restrict__ o) {
    int i = blockIdx.x * blockDim.x + threadIdx.x;
    if (i >= NB1 + NB2 + NB3) return;
    const float* src; int j = i;
    if (j < NB1) { src = g; }
    else if (j < NB1 + NB2) { src = w1; j -= NB1; }
    else { src = w2; j -= NB1 + NB2; }
    float4 v = reinterpret_cast<const float4*>(src)[j];
    ushort4 u;
    u.x = f2bf(v.x); u.y = f2bf(v.y); u.z = f2bf(v.z); u.w = f2bf(v.w);
    reinterpret_cast<ushort4*>(o)[i] = u;
}

#define GLDS16(gp, lp)                                                         \
    __builtin_amdgcn_global_load_lds(                                          \
        (__attribute__((address_space(1))) const void*)(gp),                   \
        (__attribute__((address_space(3))) void*)(lp), 16, 0, 0)

#define VMCNT(n) asm volatile("s_waitcnt vmcnt(" #n ")" ::: "memory")
#define SBAR()   __builtin_amdgcn_s_barrier()
#define SCHED0() __builtin_amdgcn_sched_barrier(0)

// ---------------- GEMM1: h = silu(gen @ w1^T), bf16 out (unchanged) ----------
__global__ __launch_bounds__(256) void gemm1_silu_kernel(
    const unsigned short* __restrict__ A,
    const unsigned short* __restrict__ Bm,
    unsigned short* __restrict__ H)
{
    __shared__ short smA[128 * 32];
    __shared__ short smB[128 * 32];
    const int m0   = blockIdx.y * 128;
    const int n0   = blockIdx.x * 128;
    const int lane = threadIdx.x & 63;
    const int wave = threadIdx.x >> 6;
    const int wm   = wave >> 1, wn = wave & 1;

    const int c0 = wave * 64 + lane;
    const int c1 = c0 + 256;
    const int rA0 = m0 + (c0 >> 2), rA1 = m0 + (c1 >> 2);
    const int rB0 = n0 + (c0 >> 2), rB1 = n0 + (c1 >> 2);
    const int ko0 = (c0 & 3) * 8,  ko1 = (c1 & 3) * 8;

    f32x4 acc[4][4] = {};

    for (int k0 = 0; k0 < DMm; k0 += 32) {
        GLDS16(A  + (size_t)rA0 * DMm + k0 + ko0, smA + wave * 512);
        GLDS16(A  + (size_t)rA1 * DMm + k0 + ko1, smA + 2048 + wave * 512);
        GLDS16(Bm + (size_t)rB0 * DMm + k0 + ko0, smB + wave * 512);
        GLDS16(Bm + (size_t)rB1 * DMm + k0 + ko1, smB + 2048 + wave * 512);
        __syncthreads();

        const int la = lane & 15, ko = (lane >> 4) * 8;
        bf16x8 af[4], bfr[4];
#pragma unroll
        for (int mm = 0; mm < 4; ++mm)
            af[mm] = *reinterpret_cast<const bf16x8*>(&smA[(wm * 64 + mm * 16 + la) * 32 + ko]);
#pragma unroll
        for (int nn = 0; nn < 4; ++nn)
            bfr[nn] = *reinterpret_cast<const bf16x8*>(&smB[(wn * 64 + nn * 16 + la) * 32 + ko]);
#pragma unroll
        for (int mm = 0; mm < 4; ++mm)
#pragma unroll
            for (int nn = 0; nn < 4; ++nn)
                acc[mm][nn] = __builtin_amdgcn_mfma_f32_16x16x32_bf16(
                    af[mm], bfr[nn], acc[mm][nn], 0, 0, 0);
        __syncthreads();
    }

#pragma unroll
    for (int mm = 0; mm < 4; ++mm) {
        int rowB = m0 + wm * 64 + mm * 16 + (lane >> 4) * 4;
#pragma unroll
        for (int nn = 0; nn < 4; ++nn) {
            int colG = n0 + wn * 64 + nn * 16 + (lane & 15);
#pragma unroll
            for (int j = 0; j < 4; ++j) {
                float v = acc[mm][nn][j];
                float s = v / (1.0f + __expf(-v));
                H[(size_t)(rowB + j) * DGg + colG] = f2bf(s);
            }
        }
    }
}

// ===== GEMM2 fused: 256n x 128t, 8 waves (64x64), ring-3 BK=32, 2 blk/CU =====
// D[n][t] = sum_k W2b[n][k] * Hb[t][k]   (n = 4d+w; conv taps w = acc reg idx j)
// Same wave geometry & occupancy as round 12 (4 waves/SIMD) but TWO blocks
// per CU = two INDEPENDENT barrier domains: one block's LDS-read burst fills
// the other block's MFMA/stage/barrier tail (m114).  LDS = 72 KB <= 80 KB.
// 8 waves: wm 0..3 (n quarters) x wn 0..1 (t halves); wave 64n x 64t;
// per region: 8 ds_read_b128 + 16 MFMA + stage (A 2 + B 1 loads/thread).
// Ledger (3 loads/thread/tile): prologue stages 0,1 -> VMCNT(3) certifies 0;
// region r (0..13) stages r+2 into par (r+2)%3 (== r-1, readers certified) ->
// VMCNT(3) certifies r+1; r=14 VMCNT(0); r=15 bare.  vmcnt BEFORE barrier.
// LDS: A[3 par][256 rows][64B] @0 (48K), B[3 par][128 rows][64B] @49152 (24K);
// post-loop overlay X f32[131][68] @0 (35.6K), Y f32[128][68] @35632.
#define LDS_B2 49152

__global__ __launch_bounds__(512, 4) void gemm2_conv_silu_kernel(
    const unsigned short* __restrict__ Hb,
    const unsigned short* __restrict__ W2b,
    const float* __restrict__ b2,
    const float* __restrict__ x,
    float* __restrict__ out)
{
    __shared__ __attribute__((aligned(16))) char lds[73728];
    const int tid  = threadIdx.x;
    const int lane = tid & 63, wave = tid >> 6;
    const int wm   = wave >> 1, wn = wave & 1;
    const int la   = lane & 15, hi = lane >> 4;

    // XCD-aware swizzle (4096 blocks, %8==0 -> bijective); t fast within XCD
    int bid = blockIdx.x;
    int swz = (bid & 7) * 512 + (bid >> 3);
    const int n0 = (swz >> 6) * 256;   // 64 n-tiles
    const int t0 = (swz & 63) * 128;   // 64 t-tiles
    const int d0 = n0 >> 2;

    const int srow = lane >> 2;                               // 0..15
    const int scol = ((lane & 3) ^ ((srow >> 1) & 3)) * 8;    // pre-swizzled src col

    auto stageA = [&](int tk, int p) {   // 2 loads/thread: 16KB tile (256 rows)
#pragma unroll
        for (int q = 0; q < 2; ++q) {
            int chunk = wave * 2 + q, row = chunk * 16 + srow;   // 0..255
            GLDS16(W2b + (size_t)(n0 + row) * DGg + tk * 32 + scol,
                   lds + p * 16384 + chunk * 1024);
        }
    };
    auto stageB = [&](int tk, int p) {   // 1 load/thread: 8KB tile (128 rows)
        int row = wave * 16 + srow;                              // 0..127
        GLDS16(Hb + (size_t)(t0 + row) * DGg + tk * 32 + scol,
               lds + LDS_B2 + p * 8192 + wave * 1024);
    };

    f32x4 acc[4][4] = {};
    const int slotb = (hi ^ ((la >> 1) & 3)) * 16;   // swizzled 16B slot
    const int aOff  = (wm * 64 + la) * 64 + slotb;
    const int bOff  = LDS_B2 + (wn * 64 + la) * 64 + slotb;

    auto region = [&](int r, bool doStage) {
        const int p = r % 3;
        const char* aB = lds + p * 16384 + aOff;
        const char* bB = lds + p * 8192 + bOff;
        bf16x8 aF[4], bF[4];
#pragma unroll
        for (int m = 0; m < 4; ++m)
            aF[m] = *reinterpret_cast<const bf16x8*>(aB + m * 1024);
#pragma unroll
        for (int nr = 0; nr < 4; ++nr)
            bF[nr] = *reinterpret_cast<const bf16x8*>(bB + nr * 1024);
        if (doStage) { stageA(r + 2, (r + 2) % 3); stageB(r + 2, (r + 2) % 3); }
        SCHED0();   // pin reads+stage above the MFMA cluster
        __builtin_amdgcn_s_setprio(1);
#pragma unroll
        for (int m = 0; m < 4; ++m)
#pragma unroll
            for (int nr = 0; nr < 4; ++nr)
                acc[m][nr] = __builtin_amdgcn_mfma_f32_16x16x32_bf16(
                    aF[m], bF[nr], acc[m][nr], 0, 0, 0);
        __builtin_amdgcn_s_setprio(0);
        SCHED0();
    };

    // ---- prologue: stage tiles 0,1 ----
    stageA(0, 0); stageB(0, 0);
    stageA(1, 1); stageB(1, 1);
    VMCNT(3);     // tile 0 certified for all waves after the barrier
    SBAR();

    // ---- main loop: 16 regions, counted vmcnt BEFORE each barrier ----
#pragma unroll
    for (int r = 0; r < 14; ++r) {
        region(r, true);
        VMCNT(3);      // certify tile r+1; tile r+2 (3 loads) in flight
        SBAR();
    }
    region(14, false); VMCNT(0); SBAR();   // certify tile 15
    region(15, false);

    // ---- x loads (post-loop; ride in regs until overlay is safe) ----
    float4 xv[5];
#pragma unroll
    for (int k = 0; k < 5; ++k) {
        int c = tid + k * 512;                   // < 2096 = 131 rows * 16 chunks
        float4 v = make_float4(0.f, 0.f, 0.f, 0.f);
        if (c < 2096) {
            int row = c >> 4, q = c & 15;
            int rg = t0 - 3 + row;
            if (rg >= 0 && (rg >> 12) == (t0 >> 12))   // zero across batch boundary
                v = *reinterpret_cast<const float4*>(&x[(size_t)rg * DD + d0 + q * 4]);
        }
        xv[k] = v;
    }
    __syncthreads();   // all K-loop LDS reads done; overlay X/Y

    float* smX = reinterpret_cast<float*>(lds);
#pragma unroll
    for (int k = 0; k < 5; ++k) {
        int c = tid + k * 512;
        if (c < 2096) {
            int row = c >> 4, q = c & 15;
            *reinterpret_cast<float4*>(&smX[row * 68 + q * 4]) = xv[k];
        }
    }
    __syncthreads();

    // ---- epilogue: bias + conv taps (reg idx j) + silu -> smY ----
    float4 bb[4];
#pragma unroll
    for (int m = 0; m < 4; ++m)
        bb[m] = *reinterpret_cast<const float4*>(&b2[n0 + wm * 64 + m * 16 + hi * 4]);

    float* smY = reinterpret_cast<float*>(lds + 35632);
#pragma unroll
    for (int nr = 0; nr < 4; ++nr) {
        int tl = wn * 64 + nr * 16 + la;
#pragma unroll
        for (int m = 0; m < 4; ++m) {
            int dl = wm * 16 + m * 4 + hi;
            float pv =
                  (acc[m][nr][0] + bb[m].x) * smX[(tl + 0) * 68 + dl]
                + (acc[m][nr][1] + bb[m].y) * smX[(tl + 1) * 68 + dl]
                + (acc[m][nr][2] + bb[m].z) * smX[(tl + 2) * 68 + dl]
                + (acc[m][nr][3] + bb[m].w) * smX[(tl + 3) * 68 + dl];
            smY[tl * 68 + dl] = pv / (1.0f + __expf(-pv));
        }
    }
    __syncthreads();

    // ---- coalesced store: 128 rows x 64 f32 (256 B per row) ----
    for (int c = tid; c < 128 * 16; c += 512) {
        int row = c >> 4, q = c & 15;
        float4 v = *reinterpret_cast<const float4*>(&smY[row * 68 + q * 4]);
        *reinterpret_cast<float4*>(&out[(size_t)(t0 + row) * DD + d0 + q * 4]) = v;
    }
}

extern "C" void kernel_launch(void* const* d_in, const int* in_sizes, int n_in,
                              void* d_out, int out_size, void* d_ws, size_t ws_size,
                              hipStream_t stream) {
    const float* x   = (const float*)d_in[0];
    const float* gen = (const float*)d_in[1];
    const float* w1  = (const float*)d_in[2];
    const float* w2  = (const float*)d_in[3];
    const float* b2  = (const float*)d_in[4];
    float* out = (float*)d_out;

    char* ws = (char*)d_ws;
    size_t off = 0;
    unsigned short* gen_b = (unsigned short*)(ws + off); off += (size_t)BT * DMm * 2;
    unsigned short* w1_b  = (unsigned short*)(ws + off); off += (size_t)DGg * DMm * 2;
    unsigned short* w2_b  = (unsigned short*)(ws + off); off += (size_t)DW * DGg * 2;
    unsigned short* h_b   = (unsigned short*)(ws + off); off += (size_t)BT * DGg * 2;

    int total4 = NB1 + NB2 + NB3;
    cast_all_kernel<<<(total4 + 255) / 256, 256, 0, stream>>>(gen, w1, w2, gen_b);

    gemm1_silu_kernel<<<dim3(DGg / 128, BT / 128), 256, 0, stream>>>(gen_b, w1_b, h_b);
    gemm2_conv_silu_kernel<<<4096, 512, 0, stream>>>(h_b, w2_b, b2, x, out);
}